// Round 6
// baseline (153.229 us; speedup 1.0000x reference)
//
#include <hip/hip_runtime.h>
#include <hip/hip_bf16.h>

#define B_ 1024
#define IN_ 512
#define OUT_ 512
#define BTILE 32
#define OTILE 32
#define ITILE 16
#define KSPLIT 4
#define KCHUNK (IN_ / KSPLIT)          // 128 i's per block
#define NCHUNKS (KCHUNK / ITILE)       // 8 staging chunks
#define XSTRIDE 34    // BTILE + 2 pad (even: keeps b64 reads 8B-aligned; 2-way banks)

typedef float v2f   __attribute__((ext_vector_type(2)));
typedef float f32x4 __attribute__((ext_vector_type(4)));
#define PKFMA(a, b, c) __builtin_elementwise_fma((v2f)(a), (v2f)(b), (v2f)(c))

__device__ __forceinline__ float fast_exp2(float x) {
#if __has_builtin(__builtin_amdgcn_exp2f)
    return __builtin_amdgcn_exp2f(x);
#else
    return __exp2f(x);
#endif
}
__device__ __forceinline__ float fast_log2(float x) {
#if __has_builtin(__builtin_amdgcn_logf)
    return __builtin_amdgcn_logf(x);
#else
    return __log2f(x);
#endif
}
__device__ __forceinline__ float fast_cos_rev(float x) {  // cos(2*pi*x), revolutions
#if __has_builtin(__builtin_amdgcn_cosf)
    return __builtin_amdgcn_cosf(x);   // ~12 busy-cyc/wave64 (R6/R14 back-solves);
                                       // poly replacement measured WORSE (R15)
#else
    return __cosf(x * 6.2831853071795864f);
#endif
}
__device__ __forceinline__ float fast_rcp(float x) {
#if __has_builtin(__builtin_amdgcn_rcpf)
    return __builtin_amdgcn_rcpf(x);
#else
    return 1.0f / x;
#endif
}

__global__ __launch_bounds__(256, 8) void chirplet_kernel(
    const float* __restrict__ x,
    const float* __restrict__ W,
    const float* __restrict__ Wc,
    const float* __restrict__ S,
    const float* __restrict__ T,
    const float* __restrict__ F,
    const float* __restrict__ bias,
    float* __restrict__ out)
{
    // R21: attack the ATOMIC TAIL. Evidence: WRITE_SIZE = KSPLIT x 2MB (32.8MB @16,
    // 76MB @32) for a 2MB output -- 8.4M clustered f32 atomics serialize at L2 in
    // the kernel drain (~20us), invariant under every compute-side restructure
    // (R16/R18/R19/R20 all failed to cut idle; busy sits at the ~49us trans floor).
    // KSPLIT 16->4 cuts atomics 4x (2.1M). Tile -> 32o x 32b keeps grid = 2048
    // = exactly 8 blocks/CU (one round). Linear silu*W path moves MFMA -> VALU
    // (+1 pkfma/unit, ~+1.7us busy; the wave/b mapping no longer fits 16x16 MFMA).
    __shared__ __align__(16) float p4_lds[ITILE * 32 * 4];   // 8 KB {a,b',c2,d2} [i][o]
    __shared__ __align__(16) float pw_lds[ITILE * 32 * 2];   // 4 KB {log2|Wc|, W} [i][o]
    __shared__ __align__(16) float x_lds[ITILE * XSTRIDE];   // 2.125 KB x fp32 [i][b]
    __shared__ __align__(16) float sl_lds[ITILE * XSTRIDE];  // 2.125 KB silu(x) [i][b]
    // total ~16.3 KB -> 8 blocks/CU (wave-cap bound)

    const int tid  = threadIdx.x;
    const int wave = tid >> 6;
    const int lane = tid & 63;
    const int o0 = blockIdx.x * OTILE;
    const int b0 = blockIdx.y * BTILE;
    const int k0 = blockIdx.z * KCHUNK;

    const int oc = lane & 15;       // o col: o = o0 + oc + o2*16
    const int lq = lane >> 4;       // b-pair: b = b0 + wave*8 + lq*2 + j

    const int pol = tid & 31;           // param o 0..31
    const int pi  = tid >> 5;           // param i slot 0..7 (stages slots pi, pi+8)

    const int xb = tid >> 3;            // x row (b) 0..31
    const int xe = tid & 7;             // x float2 pos -> i slots xe*2, xe*2+1

    const float LOG2E = 1.4426950408889634f;
    const float GK    = 0.8493218002880191f;   // sqrt(0.5*log2(e))

    v2f accc[2] = {{0.f,0.f},{0.f,0.f}};   // chirplet, v2f over b-pair, per o2
    v2f accl[2] = {{0.f,0.f},{0.f,0.f}};   // linear silu*W

    const int xoff = wave * 8 + lq * 2;

    for (int c = 0; c < NCHUNKS; ++c) {
        const int ib = k0 + c * ITILE;

        // ---- stage x tile (coalesced float2 per thread): x + silu -> [i][b] LDS
        {
            const float2 v = *(const float2*)(x + (size_t)(b0 + xb) * IN_ + ib + xe * 2);
            const float xf[2] = { v.x, v.y };
            #pragma unroll
            for (int j = 0; j < 2; ++j) {
                const int row = xe * 2 + j;
                const float xv  = xf[j];
                const float sig = fast_rcp(1.0f + fast_exp2(-xv * LOG2E));
                x_lds[row * XSTRIDE + xb]  = xv;
                sl_lds[row * XSTRIDE + xb] = xv * sig;
            }
        }

        // ---- stage params: 32 o x 16 i; each thread does slots pi and pi+8
        #pragma unroll
        for (int h = 0; h < 2; ++h) {
            const int slot = pi + h * 8;
            const size_t go = (size_t)(o0 + pol) * IN_ + ib + slot;
            const float s  = S[go];
            const float t  = T[go];
            const float f  = F[go];
            const float wc = Wc[go];
            const float w  = W[go];
            const float rs = fast_rcp(s);
            const float a  = f * rs;                       // revolutions per x
            float4 p0;
            p0.x = a;
            p0.y = -a * t + (wc < 0.0f ? 0.5f : 0.0f);     // phase + sign(Wc)
            p0.z = rs * GK;
            p0.w = -t * rs * GK;
            *(float4*)&p4_lds[(slot * 32 + pol) * 4] = p0;
            const v2f lww = { fast_log2(fabsf(wc)), w };
            *(v2f*)&pw_lds[(slot * 32 + pol) * 2] = lww;
        }
        __syncthreads();

        // ---- compute: 16 i x 2 o x (1 b-pair unit) per thread
        #pragma unroll 4
        for (int i = 0; i < ITILE; ++i) {
            const float4 abcd[2] = {
                *(const float4*)&p4_lds[(i * 32 + oc) * 4],
                *(const float4*)&p4_lds[(i * 32 + oc + 16) * 4] };
            const v2f lww[2] = {
                *(const v2f*)&pw_lds[(i * 32 + oc) * 2],
                *(const v2f*)&pw_lds[(i * 32 + oc + 16) * 2] };
            const v2f xk = *(const v2f*)&x_lds[i * XSTRIDE + xoff];
            const v2f sk = *(const v2f*)&sl_lds[i * XSTRIDE + xoff];
            #pragma unroll
            for (int o = 0; o < 2; ++o) {
                const v2f aa = { abcd[o].x, abcd[o].x };
                const v2f bb = { abcd[o].y, abcd[o].y };
                const v2f cc = { abcd[o].z, abcd[o].z };
                const v2f dd = { abcd[o].w, abcd[o].w };
                const v2f lwv = { lww[o].x, lww[o].x };
                const v2f wwv = { lww[o].y, lww[o].y };
                v2f rev = PKFMA(aa, xk, bb);        // phase (revs)
                v2f u   = PKFMA(cc, xk, dd);        // GK*(x-t)/s
                v2f arg = PKFMA(-u, u, lwv);        // lw - u^2
                v2f co, e;
                co.x = fast_cos_rev(rev.x);
                co.y = fast_cos_rev(rev.y);
                e.x  = fast_exp2(arg.x);
                e.y  = fast_exp2(arg.y);
                accc[o] = PKFMA(co, e, accc[o]);    // chirplet
                accl[o] = PKFMA(wwv, sk, accl[o]);  // linear silu*W
            }
        }
        __syncthreads();
    }

    // ---- epilogue: 4 atomics/thread (vs 16 in R18)
    const float badd[2] = { (blockIdx.z == 0) ? bias[o0 + oc] : 0.0f,
                            (blockIdx.z == 0) ? bias[o0 + oc + 16] : 0.0f };
    #pragma unroll
    for (int o = 0; o < 2; ++o) {
        #pragma unroll
        for (int j = 0; j < 2; ++j) {
            const int b = b0 + wave * 8 + lq * 2 + j;
            float* dst = &out[(size_t)b * OUT_ + o0 + oc + o * 16];
            const float val = (j == 0 ? accc[o].x : accc[o].y)
                            + (j == 0 ? accl[o].x : accl[o].y) + badd[o];
#if defined(__HIP_DEVICE_COMPILE__)
            unsafeAtomicAdd(dst, val);   // HW global_atomic_add_f32
#else
            atomicAdd(dst, val);
#endif
        }
    }
}

extern "C" void kernel_launch(void* const* d_in, const int* in_sizes, int n_in,
                              void* d_out, int out_size, void* d_ws, size_t ws_size,
                              hipStream_t stream) {
    const float* x    = (const float*)d_in[0];
    const float* W    = (const float*)d_in[1];
    const float* Wc   = (const float*)d_in[2];
    const float* S    = (const float*)d_in[3];
    const float* T    = (const float*)d_in[4];
    const float* F    = (const float*)d_in[5];
    const float* bias = (const float*)d_in[6];
    float* out = (float*)d_out;

    // d_out is poisoned before every launch; atomics need zeroed destination
    hipMemsetAsync(out, 0, (size_t)out_size * sizeof(float), stream);

    dim3 grid(OUT_ / OTILE, B_ / BTILE, KSPLIT);   // 16 x 32 x 4 = 2048 blocks = 8/CU
    chirplet_kernel<<<grid, 256, 0, stream>>>(x, W, Wc, S, T, F, bias, out);
}

// Round 7
// 127.442 us; speedup vs baseline: 1.2023x; 1.2023x over previous
//
#include <hip/hip_runtime.h>
#include <hip/hip_bf16.h>

#define B_ 1024
#define IN_ 512
#define OUT_ 512
#define BTILE 64
#define OTILE 16
#define ITILE 16
#define KSPLIT 8
#define KCHUNK (IN_ / KSPLIT)          // 64 i's per block
#define NCHUNKS (KCHUNK / ITILE)       // 4 staging chunks
#define P4ROW 68   // floats per i-row of p4 (16 o * 4 + 4 pad; de-phases banks per i)
#define PLROW 17   // floats per i-row of lw (16 + 1 pad)
#define XROW  68   // floats per i-row of x (64 b + 4 pad; b128 reads stay 16B-aligned)
#define SAROW 24   // ushorts per b-row of sA/wB (16 k + 8 pad = 48 B, 16B-aligned, 2-way banks)

typedef float v2f   __attribute__((ext_vector_type(2)));
typedef float f32x4 __attribute__((ext_vector_type(4)));
typedef short s16x8 __attribute__((ext_vector_type(8)));   // 8 bf16 = 4 VGPRs
#define PKFMA(a, b, c) __builtin_elementwise_fma((v2f)(a), (v2f)(b), (v2f)(c))

__device__ __forceinline__ unsigned short f2bf(float f) {
    union { float f; unsigned int u; } v; v.f = f;
    unsigned int b = v.u + 0x7FFFu + ((v.u >> 16) & 1u);   // RNE
    return (unsigned short)(b >> 16);
}
__device__ __forceinline__ float fast_exp2(float x) {
#if __has_builtin(__builtin_amdgcn_exp2f)
    return __builtin_amdgcn_exp2f(x);
#else
    return __exp2f(x);
#endif
}
__device__ __forceinline__ float fast_log2(float x) {
#if __has_builtin(__builtin_amdgcn_logf)
    return __builtin_amdgcn_logf(x);
#else
    return __log2f(x);
#endif
}
__device__ __forceinline__ float fast_cos_rev(float x) {  // cos(2*pi*x), revolutions
#if __has_builtin(__builtin_amdgcn_cosf)
    return __builtin_amdgcn_cosf(x);   // ~12 busy-cyc/wave64 (R6/R14 back-solves);
                                       // poly replacement measured WORSE (R15)
#else
    return __cosf(x * 6.2831853071795864f);
#endif
}
__device__ __forceinline__ float fast_rcp(float x) {
#if __has_builtin(__builtin_amdgcn_rcpf)
    return __builtin_amdgcn_rcpf(x);
#else
    return 1.0f / x;
#endif
}

__global__ __launch_bounds__(256, 8) void chirplet_kernel(
    const float* __restrict__ x,
    const float* __restrict__ W,
    const float* __restrict__ Wc,
    const float* __restrict__ S,
    const float* __restrict__ T,
    const float* __restrict__ F,
    const float* __restrict__ bias,
    float* __restrict__ out)
{
    // R22: all three verified levers at once.
    //  (1) LDS intensity: 1 o x 4 b per thread -> ~10 B/unit/lane (delivery ~30us,
    //      under the ~50us busy floor; R21's 100us proved >24 B/unit is fatal).
    //  (2) 2 resident rounds: grid 32x16x8 = 4096 blocks -> backfill covers
    //      stragglers, round-2 compute overlaps round-1 atomic drain (R14's edge).
    //  (3) atomic traffic: KSPLIT 16->8 halves atomics to 4.2M (WRITE ~16 MB).
    //  Micro-MFMA keeps silu*W on the matrix pipe: each wave's 16 b-rows x 16 o
    //  fit the 16x16x32 tile (K=16/chunk via lanes 0-31; lanes 32-63 zero) --
    //  same fragment mapping as the proven R14 kernel. z-blocks of one tile
    //  differ by 512 in flat id (=0 mod 8) -> same XCD -> L2-local atomics.
    __shared__ __align__(16) float p4_lds[ITILE * P4ROW];    // 4.25 KB {a,b',c2,d2} [i][o]
    __shared__ __align__(16) float plw_lds[ITILE * PLROW];   // 1.06 KB log2|Wc| [i][o]
    __shared__ __align__(16) float x_lds[ITILE * XROW];      // 4.25 KB x fp32 [i][b]
    __shared__ __align__(16) unsigned short sA_lds[BTILE * SAROW]; // 3 KB silu bf16 [b][k16]
    __shared__ __align__(16) unsigned short wB_lds[OTILE * SAROW]; // 0.75 KB W bf16 [o][k16]
    // total ~13.3 KB -> 8 blocks/CU (wave-cap bound)

    const int tid  = threadIdx.x;
    const int wave = tid >> 6;
    const int lane = tid & 63;
    const int o0 = blockIdx.x * OTILE;
    const int b0 = blockIdx.y * BTILE;
    const int k0 = blockIdx.z * KCHUNK;

    const int oc = lane & 15;       // o col (MFMA C col); o = o0 + oc
    const int lq = lane >> 4;       // b quad: b = b0 + wave*16 + lq*4 + reg (MFMA C row)

    const int xr = tid >> 2;            // x stage: b row 0..63
    const int xq = tid & 3;             // i quad: i = xq*4 + j (64B-coalesced)

    const int po = tid & 15;            // param o 0..15
    const int pi = tid >> 4;            // param i 0..15

    const float LOG2E = 1.4426950408889634f;
    const float GK    = 0.8493218002880191f;   // sqrt(0.5*log2(e))

    v2f acc2[2] = {{0.f,0.f},{0.f,0.f}};       // chirplet: unit p covers b regs p*2, p*2+1
    f32x4 accg = { 0.f, 0.f, 0.f, 0.f };       // MFMA accumulator (same C layout)

    const int xb = wave * 16 + lq * 4;

    for (int c = 0; c < NCHUNKS; ++c) {
        const int ib = k0 + c * ITILE;

        // ---- stage x tile: x fp32 -> x_lds[i][b]; silu bf16 -> sA_lds[b][k]
        {
            const float4 v = *(const float4*)(x + (size_t)(b0 + xr) * IN_ + ib + xq * 4);
            const float xf[4] = { v.x, v.y, v.z, v.w };
            unsigned int pk[2] = { 0u, 0u };
            #pragma unroll
            for (int j = 0; j < 4; ++j) {
                const int row = xq * 4 + j;
                const float xv  = xf[j];
                const float sig = fast_rcp(1.0f + fast_exp2(-xv * LOG2E));
                x_lds[row * XROW + xr] = xv;
                pk[j >> 1] |= (unsigned int)f2bf(xv * sig) << (16 * (j & 1));
            }
            *(uint2*)&sA_lds[xr * SAROW + xq * 4] = make_uint2(pk[0], pk[1]);
        }

        // ---- stage params: 16 o x 16 i, one element/thread
        {
            const size_t go = (size_t)(o0 + po) * IN_ + ib + pi;
            const float s  = S[go];
            const float t  = T[go];
            const float f  = F[go];
            const float wc = Wc[go];
            const float w  = W[go];
            const float rs = fast_rcp(s);
            const float a  = f * rs;                       // revolutions per x
            float4 p0;
            p0.x = a;
            p0.y = -a * t + (wc < 0.0f ? 0.5f : 0.0f);     // phase + sign(Wc)
            p0.z = rs * GK;
            p0.w = -t * rs * GK;
            *(float4*)&p4_lds[pi * P4ROW + po * 4] = p0;
            plw_lds[pi * PLROW + po] = fast_log2(fabsf(wc));
            wB_lds[po * SAROW + pi] = f2bf(w);
        }
        __syncthreads();

        // ---- micro-GEMM on matrix pipe: K=16 valid (lanes 0-31), accumulate in C
        {
            s16x8 af = {0,0,0,0,0,0,0,0}, bf = af;
            if (lane < 32) {
                const int q8 = (lane >> 4) * 8;            // k group 0..7 / 8..15
                af = *(const s16x8*)&sA_lds[(wave * 16 + oc) * SAROW + q8];
                bf = *(const s16x8*)&wB_lds[oc * SAROW + q8];
            }
            accg = __builtin_amdgcn_mfma_f32_16x16x32_bf16(af, bf, accg, 0, 0, 0);
        }

        // ---- compute: chirplet, 16 i x 1 o x 2 b-pair units per thread
        #pragma unroll 4
        for (int i = 0; i < ITILE; ++i) {
            const float4 abcd = *(const float4*)&p4_lds[i * P4ROW + oc * 4];
            const float  lw   = plw_lds[i * PLROW + oc];
            const f32x4  xk4  = *(const f32x4*)&x_lds[i * XROW + xb];
            const v2f xk2[2] = {
                __builtin_shufflevector(xk4, xk4, 0, 1),
                __builtin_shufflevector(xk4, xk4, 2, 3) };
            const v2f aa = { abcd.x, abcd.x };
            const v2f bb = { abcd.y, abcd.y };
            const v2f cc = { abcd.z, abcd.z };
            const v2f dd = { abcd.w, abcd.w };
            const v2f lwv = { lw, lw };
            #pragma unroll
            for (int p = 0; p < 2; ++p) {
                v2f rev = PKFMA(aa, xk2[p], bb);       // phase (revs)
                v2f u   = PKFMA(cc, xk2[p], dd);       // GK*(x-t)/s
                v2f arg = PKFMA(-u, u, lwv);           // lw - u^2
                v2f co, e;
                co.x = fast_cos_rev(rev.x);
                co.y = fast_cos_rev(rev.y);
                e.x  = fast_exp2(arg.x);
                e.y  = fast_exp2(arg.y);
                acc2[p] = PKFMA(co, e, acc2[p]);       // chirplet
            }
        }
        __syncthreads();
    }

    // ---- epilogue: chirplet + MFMA (same C layout) + bias; 4 atomics/thread
    const float badd = (blockIdx.z == 0) ? bias[o0 + oc] : 0.0f;
    #pragma unroll
    for (int p = 0; p < 2; ++p) {
        #pragma unroll
        for (int j = 0; j < 2; ++j) {
            const int reg = p * 2 + j;
            const int b = b0 + wave * 16 + lq * 4 + reg;
            float* dst = &out[(size_t)b * OUT_ + o0 + oc];
            const float val = (j == 0 ? acc2[p].x : acc2[p].y) + accg[reg] + badd;
#if defined(__HIP_DEVICE_COMPILE__)
            unsafeAtomicAdd(dst, val);   // HW global_atomic_add_f32
#else
            atomicAdd(dst, val);
#endif
        }
    }
}

extern "C" void kernel_launch(void* const* d_in, const int* in_sizes, int n_in,
                              void* d_out, int out_size, void* d_ws, size_t ws_size,
                              hipStream_t stream) {
    const float* x    = (const float*)d_in[0];
    const float* W    = (const float*)d_in[1];
    const float* Wc   = (const float*)d_in[2];
    const float* S    = (const float*)d_in[3];
    const float* T    = (const float*)d_in[4];
    const float* F    = (const float*)d_in[5];
    const float* bias = (const float*)d_in[6];
    float* out = (float*)d_out;

    // d_out is poisoned before every launch; atomics need zeroed destination
    hipMemsetAsync(out, 0, (size_t)out_size * sizeof(float), stream);

    dim3 grid(OUT_ / OTILE, B_ / BTILE, KSPLIT);   // 32 x 16 x 8 = 4096 blocks = 2 rounds
    chirplet_kernel<<<grid, 256, 0, stream>>>(x, W, Wc, S, T, F, bias, out);
}